// Round 14
// baseline (29.731 us; speedup 1.0000x reference)
//
#include <hip/hip_runtime.h>
#include <math.h>

// Problem constants: B=256, N=64, M=64, d=32, TOPK=10
constexpr int Bn = 256;
constexpr int Nn = 64;
constexpr int Mn = 64;
constexpr int Dn = 32;
constexpr int TK = 10;
constexpr int NT = 1024;   // 16 waves
constexpr int NBLK = Bn * 2;   // 2 blocks/batch: 32 output rows each, full K/V/lam each

typedef float v2f __attribute__((ext_vector_type(2)));

// Correctly-rounded fp32 exp via fp64 (matches np within <=0.5 ulp)
__device__ __forceinline__ float exp_np(float x) {
    return (float)exp((double)x);
}
// Monotone fp32 -> uint32 order map (weights finite; no NaNs)
__device__ __forceinline__ unsigned int f2u(float f) {
    unsigned int b = __float_as_uint(f);
    return (b & 0x80000000u) ? ~b : (b | 0x80000000u);
}
__device__ __forceinline__ float u2f(unsigned int u) {
    return __uint_as_float((u & 0x80000000u) ? (u ^ 0x80000000u) : ~u);
}

__global__ __launch_bounds__(NT, 8) void sparse_lambda_attn_kernel(
    const float* __restrict__ fv,   // [B,N,D]
    const float* __restrict__ cv,   // [B,M,D]
    const float* __restrict__ Wq,   // [D,D]
    const float* __restrict__ Wk,   // [D,D]
    const float* __restrict__ Wv,   // [D,M]
    float* __restrict__ out)        // [B, N*TK, D]
{
    // Replicate numpy fp32 semantics: NO fma contraction anywhere in this kernel.
    #pragma clang fp contract(off)

    __shared__ float cT[Dn][65];     // 8.1 KB [d][m]
    __shared__ float c_row[Mn][36];  // 9 KB   [m][d] (output gather)
    __shared__ float fT[Dn][33];     // 4.1 KB [d][n_local] (this block's 32 rows)
    __shared__ float f_row[32][36];  // 4.5 KB [n_local][d]
    __shared__ float KpT[Dn][68];    // 8.5 KB [k][m] K probabilities
    __shared__ float QmT[Dn][36];    // 4.5 KB [k][n_local]
    __shared__ float Vs[Mn][68];     // 17 KB  [m][v]
    __shared__ float lamS[Dn][68];   // 8.5 KB [k][v]
    __shared__ float topw[32][TK];   // 1.25 KB
    __shared__ int   topi[32][TK];   // 1.25 KB
    // total ~66.8 KB -> 2 blocks/CU

    const int bid  = blockIdx.x;
    const int b    = bid >> 1;
    const int n0   = (bid & 1) << 5;   // this block's output rows n0..n0+31
    const int tid  = threadIdx.x;
    const int lane = tid & 63;
    const int wid  = tid >> 6;

    // ---- stage: c -> c_row + cT (512 thr); f rows n0..n0+31 -> f_row + fT (256 thr) ----
    if (tid < 512) {
        const float4 v = reinterpret_cast<const float4*>(cv + (size_t)b * Mn * Dn)[tid];
        const int m = tid >> 3, d4 = (tid & 7) << 2;
        *reinterpret_cast<float4*>(&c_row[m][d4]) = v;
        cT[d4 + 0][m] = v.x; cT[d4 + 1][m] = v.y; cT[d4 + 2][m] = v.z; cT[d4 + 3][m] = v.w;
    } else if (tid < 768) {
        const int t = tid - 512;   // 0..255
        const float4 v = reinterpret_cast<const float4*>(fv + (size_t)b * Nn * Dn)[(n0 << 3) + t];
        const int n = t >> 3, d4 = (t & 7) << 2;
        *reinterpret_cast<float4*>(&f_row[n][d4]) = v;
        fT[d4 + 0][n] = v.x; fT[d4 + 1][n] = v.y; fT[d4 + 2][n] = v.z; fT[d4 + 3][n] = v.w;
    }
    __syncthreads();

    // ---- Phase A (one barrier):
    //   waves 0-7:  K cols 4w..4w+3 + FULL wave-local softmax (r12's exact code)
    //   waves 8-15: V cols 8q..8q+7 (lane=m) AND Q cols 4q..4q+3 for this block's 32 rows
    //   W via wave-uniform pointers -> s_load scalar cache.
    if (wid < 8) {
        const int kq = __builtin_amdgcn_readfirstlane(wid);
        const int m = lane;
        const float* wkq = Wk + (kq << 2);
        float a0 = 0.f, a1 = 0.f, a2 = 0.f, a3 = 0.f;
        #pragma unroll 8
        for (int d = 0; d < Dn; ++d) {
            const float cc = cT[d][m];
            const float* wr = wkq + d * Dn;
            const float w0 = wr[0], w1 = wr[1], w2 = wr[2], w3 = wr[3];
            a0 = a0 + cc * w0;  a1 = a1 + cc * w1;  a2 = a2 + cc * w2;  a3 = a3 + cc * w3;
        }
        // column max via xor shuffle trees (fmax exactly order-independent)
        float m0 = a0, m1 = a1, m2 = a2, m3 = a3;
        #pragma unroll
        for (int off = 1; off < 64; off <<= 1) {
            m0 = fmaxf(m0, __shfl_xor(m0, off));
            m1 = fmaxf(m1, __shfl_xor(m1, off));
            m2 = fmaxf(m2, __shfl_xor(m2, off));
            m3 = fmaxf(m3, __shfl_xor(m3, off));
        }
        // exp (np: elementwise), stash to LDS
        const float e0 = exp_np(a0 - m0), e1 = exp_np(a1 - m1);
        const float e2 = exp_np(a2 - m2), e3 = exp_np(a3 - m3);
        KpT[(kq << 2) + 0][m] = e0;
        KpT[(kq << 2) + 1][m] = e1;
        KpT[(kq << 2) + 2][m] = e2;
        KpT[(kq << 2) + 3][m] = e3;
        // ascending-m ordered sum (np.sum order), one lane per column (wave-local)
        float s = 0.f;
        if (lane < 4) {
            const int col = (kq << 2) + lane;
            for (int mm = 0; mm < Mn; ++mm) s = s + KpT[col][mm];
        }
        const float s0 = __shfl(s, 0), s1 = __shfl(s, 1);
        const float s2 = __shfl(s, 2), s3 = __shfl(s, 3);
        // true division, final probabilities
        KpT[(kq << 2) + 0][m] = e0 / s0;
        KpT[(kq << 2) + 1][m] = e1 / s1;
        KpT[(kq << 2) + 2][m] = e2 / s2;
        KpT[(kq << 2) + 3][m] = e3 / s3;
    } else {
        const int q  = __builtin_amdgcn_readfirstlane(wid - 8);
        const int m  = lane;          // V row
        const int nl = lane & 31;     // Q row (both half-waves compute same rows; lanes<32 store)
        const float* wqq = Wq + (q << 2);
        const float* wvq = Wv + (q << 3);
        float q0 = 0.f, q1 = 0.f, q2 = 0.f, q3 = 0.f;
        float b0 = 0.f, b1 = 0.f, b2 = 0.f, b3 = 0.f;
        float b4 = 0.f, b5 = 0.f, b6 = 0.f, b7 = 0.f;
        #pragma unroll 4
        for (int d = 0; d < Dn; ++d) {
            const float cc = cT[d][m];
            const float ff = fT[d][nl];
            const float* wr = wqq + d * Dn;
            const float* ur = wvq + d * Mn;
            const float w0 = wr[0], w1 = wr[1], w2 = wr[2], w3 = wr[3];
            const float u0 = ur[0], u1 = ur[1], u2 = ur[2], u3 = ur[3];
            const float u4 = ur[4], u5 = ur[5], u6 = ur[6], u7 = ur[7];
            q0 = q0 + ff * w0;  q1 = q1 + ff * w1;  q2 = q2 + ff * w2;  q3 = q3 + ff * w3;
            b0 = b0 + cc * u0;  b1 = b1 + cc * u1;  b2 = b2 + cc * u2;  b3 = b3 + cc * u3;
            b4 = b4 + cc * u4;  b5 = b5 + cc * u5;  b6 = b6 + cc * u6;  b7 = b7 + cc * u7;
        }
        if (lane < 32) {
            QmT[(q << 2) + 0][nl] = q0;
            QmT[(q << 2) + 1][nl] = q1;
            QmT[(q << 2) + 2][nl] = q2;
            QmT[(q << 2) + 3][nl] = q3;
        }
        float4 r0; r0.x = b0; r0.y = b1; r0.z = b2; r0.w = b3;
        float4 r1; r1.x = b4; r1.y = b5; r1.z = b6; r1.w = b7;
        *reinterpret_cast<float4*>(&Vs[m][(q << 3) + 0]) = r0;
        *reinterpret_cast<float4*>(&Vs[m][(q << 3) + 4]) = r1;
    }
    __syncthreads();

    // ---- lam[k][v] = sum_m K[m][k]*V[m][v]: ALL 1024 threads, (k, v2), packed (r13 form) ----
    {
        const int k = tid >> 5;
        const int v2 = (tid & 31) << 1;
        v2f acc = {0.f, 0.f};
        for (int m = 0; m < Mn; ++m) {
            const float kk = KpT[k][m];
            const float2 vv = *reinterpret_cast<const float2*>(&Vs[m][v2]);
            const v2f kv = {kk, kk};
            const v2f vvv = {vv.x, vv.y};
            acc = acc + kv * vvv;
        }
        float2 r; r.x = acc.x; r.y = acc.y;
        *reinterpret_cast<float2*>(&lamS[k][v2]) = r;
    }
    __syncthreads();

    // ---- weight (np-exact ascending-k) FUSED with top-10 + softmax: 32 rows x 16 lanes ----
    if (tid < 512) {
        const int nl = tid >> 4;     // 0..31
        const int g  = tid & 15;
        const int v4 = g << 2;
        float a0 = 0.f, a1 = 0.f, a2 = 0.f, a3 = 0.f;
        for (int k = 0; k < Dn; ++k) {
            const float qq = QmT[k][nl];
            const float4 lv = *reinterpret_cast<const float4*>(&lamS[k][v4]);
            a0 = a0 + qq * lv.x;  a1 = a1 + qq * lv.y;  a2 = a2 + qq * lv.z;  a3 = a3 + qq * lv.w;
        }

        unsigned su0 = f2u(a0), su1 = f2u(a1), su2 = f2u(a2), su3 = f2u(a3);
        unsigned avail = 0xFu;
        float val0 = 0.f, myval = 0.f;
        int   myidx = 0;

        #pragma unroll
        for (int t = 0; t < TK; ++t) {
            unsigned bu = 0u; int bm = 64;
            if ((avail & 1u) && su0 > bu) { bu = su0; bm = (g << 2) + 0; }
            if ((avail & 2u) && su1 > bu) { bu = su1; bm = (g << 2) + 1; }
            if ((avail & 4u) && su2 > bu) { bu = su2; bm = (g << 2) + 2; }
            if ((avail & 8u) && su3 > bu) { bu = su3; bm = (g << 2) + 3; }
            #pragma unroll
            for (int off = 1; off <= 8; off <<= 1) {
                const unsigned ou = __shfl_xor(bu, off);
                const int      om = __shfl_xor(bm, off);
                if (ou > bu || (ou == bu && om < bm)) { bu = ou; bm = om; }
            }
            const float bv = u2f(bu);
            if (t == 0) val0 = bv;
            if (g == t) { myval = bv; myidx = bm; }
            if ((bm >> 2) == g) avail &= ~(1u << (bm & 3));
        }

        const float ev_own = (g < TK) ? exp_np(myval - val0) : 0.f;
        float s = 0.f;
        #pragma unroll
        for (int t = 0; t < TK; ++t) {
            const float e = __shfl(ev_own, (lane & 48) + t);
            s = s + e;
        }
        if (g < TK) {
            topw[nl][g] = ev_own / s;
            topi[nl][g] = myidx;
        }
    }
    __syncthreads();

    // ---- output: rows n0..n0+31: out[b][(n0+n)*TK+t][d] = w * (f[n][d]*c[idx][d]) ----
    float* ob = out + (size_t)b * (Nn * TK * Dn) + (size_t)n0 * (TK * Dn);
    #pragma unroll
    for (int p = 0; p < 3; ++p) {
        const int i = tid + (p << 10);       // 0..2559 f4 (32 rows x 80 f4)
        if (i < 2560) {
            const int n = i / 80;
            const int r = i - n * 80;
            const int t = r >> 3;
            const int d4 = (r & 7) << 2;
            const float w = topw[n][t];
            const int m = topi[n][t];
            const float4 fr = *reinterpret_cast<const float4*>(&f_row[n][d4]);
            const float4 cr = *reinterpret_cast<const float4*>(&c_row[m][d4]);
            float4 o;
            { const float vx = fr.x * cr.x; o.x = w * vx; }
            { const float vy = fr.y * cr.y; o.y = w * vy; }
            { const float vz = fr.z * cr.z; o.z = w * vz; }
            { const float vw = fr.w * cr.w; o.w = w * vw; }
            reinterpret_cast<float4*>(ob)[i] = o;
        }
    }
}

extern "C" void kernel_launch(void* const* d_in, const int* in_sizes, int n_in,
                              void* d_out, int out_size, void* d_ws, size_t ws_size,
                              hipStream_t stream) {
    const float* fv = (const float*)d_in[0];   // featureVec [256,64,32]
    const float* cv = (const float*)d_in[1];   // contextVec [256,64,32]
    const float* Wq = (const float*)d_in[2];   // [32,32]
    const float* Wk = (const float*)d_in[3];   // [32,32]
    const float* Wv = (const float*)d_in[4];   // [32,64]
    float* out = (float*)d_out;                // [256, 640, 32]

    sparse_lambda_attn_kernel<<<NBLK, NT, 0, stream>>>(fv, cv, Wq, Wk, Wv, out);
}

// Round 15
// 24.347 us; speedup vs baseline: 1.2211x; 1.2211x over previous
//
#include <hip/hip_runtime.h>
#include <math.h>

// Problem constants: B=256, N=64, M=64, d=32, TOPK=10
constexpr int Bn = 256;
constexpr int Nn = 64;
constexpr int Mn = 64;
constexpr int Dn = 32;
constexpr int TK = 10;
constexpr int NT = 1024;   // 16 waves

typedef float v2f __attribute__((ext_vector_type(2)));   // -> v_pk_*_f32

// Correctly-rounded fp32 exp via fp64 (matches np within <=0.5 ulp)
__device__ __forceinline__ float exp_np(float x) {
    return (float)exp((double)x);
}
// Monotone fp32 -> uint32 order map (weights finite; no NaNs)
__device__ __forceinline__ unsigned int f2u(float f) {
    unsigned int b = __float_as_uint(f);
    return (b & 0x80000000u) ? ~b : (b | 0x80000000u);
}
__device__ __forceinline__ float u2f(unsigned int u) {
    return __uint_as_float((u & 0x80000000u) ? (u ^ 0x80000000u) : ~u);
}

__global__ __launch_bounds__(NT, 8) void sparse_lambda_attn_kernel(
    const float* __restrict__ fv,   // [B,N,D]
    const float* __restrict__ cv,   // [B,M,D]
    const float* __restrict__ Wq,   // [D,D]
    const float* __restrict__ Wk,   // [D,D]
    const float* __restrict__ Wv,   // [D,M]
    float* __restrict__ out)        // [B, N*TK, D]
{
    // Replicate numpy fp32 semantics: NO fma contraction anywhere in this kernel.
    #pragma clang fp contract(off)

    // Swizzled row-major tiles: float4-slot j of row r lives at slot j^(r&7).
    __shared__ float f_sw[Nn][32];   // 8 KB
    __shared__ float c_sw[Mn][32];   // 8 KB
    __shared__ float KpT[Dn][68];    // 8.5 KB [k][m] K probabilities
    __shared__ float QmT[Dn][68];    // 8.5 KB [k][n]
    __shared__ float Vs[Mn][68];     // 17 KB  [m][v]
    __shared__ float lamS[Dn][68];   // 8.5 KB [k][v]
    // total ~58.5 KB

    const int b    = blockIdx.x;
    const int tid  = threadIdx.x;
    const int lane = tid & 63;
    const int wid  = tid >> 6;

    // ---- stage: f,c -> swizzled row-major LDS (coalesced f4 global reads) ----
    if (tid < 512) {
        const float4 v = reinterpret_cast<const float4*>(fv + (size_t)b * Nn * Dn)[tid];
        const int n = tid >> 3, j = tid & 7;
        *reinterpret_cast<float4*>(&f_sw[n][(j ^ (n & 7)) << 2]) = v;
    } else {
        const int t = tid - 512;
        const float4 v = reinterpret_cast<const float4*>(cv + (size_t)b * Mn * Dn)[t];
        const int m = t >> 3, j = t & 7;
        *reinterpret_cast<float4*>(&c_sw[m][(j ^ (m & 7)) << 2]) = v;
    }
    __syncthreads();

    // ---- Phase A (one barrier):
    //   waves 0-7:  K cols 4w..4w+3 + FULL wave-local softmax (r13 code, passed)
    //   waves 8-15: Q cols 4q..4q+3 AND V cols 8q..8q+7 (lane = row)
    //   W via wave-uniform pointers -> s_load scalar cache.
    if (wid < 8) {
        const int kq = __builtin_amdgcn_readfirstlane(wid);
        const int m = lane;
        const float* wkq = Wk + (kq << 2);
        v2f a01 = {0.f, 0.f}, a23 = {0.f, 0.f};
        #pragma unroll
        for (int j = 0; j < 8; ++j) {
            const float4 cf = *reinterpret_cast<const float4*>(&c_sw[m][(j ^ (m & 7)) << 2]);
            const float cvs[4] = {cf.x, cf.y, cf.z, cf.w};
            #pragma unroll
            for (int dd = 0; dd < 4; ++dd) {
                const int d = (j << 2) + dd;
                const float* wr = wkq + d * Dn;
                const v2f w01 = {wr[0], wr[1]};
                const v2f w23 = {wr[2], wr[3]};
                const v2f cc  = {cvs[dd], cvs[dd]};
                a01 = a01 + cc * w01;
                a23 = a23 + cc * w23;
            }
        }
        float a0 = a01.x, a1 = a01.y, a2 = a23.x, a3 = a23.y;
        float m0 = a0, m1 = a1, m2 = a2, m3 = a3;
        #pragma unroll
        for (int off = 1; off < 64; off <<= 1) {
            m0 = fmaxf(m0, __shfl_xor(m0, off));
            m1 = fmaxf(m1, __shfl_xor(m1, off));
            m2 = fmaxf(m2, __shfl_xor(m2, off));
            m3 = fmaxf(m3, __shfl_xor(m3, off));
        }
        const float e0 = exp_np(a0 - m0), e1 = exp_np(a1 - m1);
        const float e2 = exp_np(a2 - m2), e3 = exp_np(a3 - m3);
        KpT[(kq << 2) + 0][m] = e0;
        KpT[(kq << 2) + 1][m] = e1;
        KpT[(kq << 2) + 2][m] = e2;
        KpT[(kq << 2) + 3][m] = e3;
        // ascending-m ordered sum (np.sum order), one lane per column (wave-local)
        float s = 0.f;
        if (lane < 4) {
            const int col = (kq << 2) + lane;
            for (int mm = 0; mm < Mn; ++mm) s = s + KpT[col][mm];
        }
        const float s0 = __shfl(s, 0), s1 = __shfl(s, 1);
        const float s2 = __shfl(s, 2), s3 = __shfl(s, 3);
        KpT[(kq << 2) + 0][m] = e0 / s0;
        KpT[(kq << 2) + 1][m] = e1 / s1;
        KpT[(kq << 2) + 2][m] = e2 / s2;
        KpT[(kq << 2) + 3][m] = e3 / s3;
    } else {
        const int q = __builtin_amdgcn_readfirstlane(wid - 8);
        const int nm = lane;
        const float* wqq = Wq + (q << 2);
        const float* wvq = Wv + (q << 3);
        v2f q01 = {0.f, 0.f}, q23 = {0.f, 0.f};
        v2f b01 = {0.f, 0.f}, b23 = {0.f, 0.f}, b45 = {0.f, 0.f}, b67 = {0.f, 0.f};
        #pragma unroll
        for (int j = 0; j < 8; ++j) {
            const int sl = (j ^ (nm & 7)) << 2;
            const float4 ff4 = *reinterpret_cast<const float4*>(&f_sw[nm][sl]);
            const float4 cf4 = *reinterpret_cast<const float4*>(&c_sw[nm][sl]);
            const float fvs[4] = {ff4.x, ff4.y, ff4.z, ff4.w};
            const float cvs[4] = {cf4.x, cf4.y, cf4.z, cf4.w};
            #pragma unroll
            for (int dd = 0; dd < 4; ++dd) {
                const int d = (j << 2) + dd;
                const float* wr = wqq + d * Dn;
                const float* ur = wvq + d * Mn;
                const v2f wq01 = {wr[0], wr[1]};
                const v2f wq23 = {wr[2], wr[3]};
                const v2f u01 = {ur[0], ur[1]};
                const v2f u23 = {ur[2], ur[3]};
                const v2f u45 = {ur[4], ur[5]};
                const v2f u67 = {ur[6], ur[7]};
                const v2f ffv = {fvs[dd], fvs[dd]};
                const v2f ccv = {cvs[dd], cvs[dd]};
                q01 = q01 + ffv * wq01;
                q23 = q23 + ffv * wq23;
                b01 = b01 + ccv * u01;
                b23 = b23 + ccv * u23;
                b45 = b45 + ccv * u45;
                b67 = b67 + ccv * u67;
            }
        }
        QmT[(q << 2) + 0][nm] = q01.x;
        QmT[(q << 2) + 1][nm] = q01.y;
        QmT[(q << 2) + 2][nm] = q23.x;
        QmT[(q << 2) + 3][nm] = q23.y;
        float4 r0; r0.x = b01.x; r0.y = b01.y; r0.z = b23.x; r0.w = b23.y;
        float4 r1; r1.x = b45.x; r1.y = b45.y; r1.z = b67.x; r1.w = b67.y;
        *reinterpret_cast<float4*>(&Vs[nm][(q << 3) + 0]) = r0;
        *reinterpret_cast<float4*>(&Vs[nm][(q << 3) + 4]) = r1;
    }
    __syncthreads();

    // ---- lam[k][v] = sum_m K[m][k]*V[m][v]: 512 threads, (k, v4), ascending m (r12 form) ----
    if (tid < 512) {
        const int k = tid >> 4, v4 = (tid & 15) << 2;
        float a0 = 0.f, a1 = 0.f, a2 = 0.f, a3 = 0.f;
        for (int m = 0; m < Mn; ++m) {
            const float kk = KpT[k][m];
            const float4 vv = *reinterpret_cast<const float4*>(&Vs[m][v4]);
            a0 = a0 + kk * vv.x;  a1 = a1 + kk * vv.y;  a2 = a2 + kk * vv.z;  a3 = a3 + kk * vv.w;
        }
        float4 r; r.x = a0; r.y = a1; r.z = a2; r.w = a3;
        *reinterpret_cast<float4*>(&lamS[k][v4]) = r;
    }
    __syncthreads();

    // ---- WAVE-LOCAL tail: weight -> top-10 -> softmax -> output for rows 4*wid..4*wid+3.
    // No further barriers; w/idx carried in registers via __shfl; writes stagger per wave.
    {
        const int nl = tid >> 4;     // global row 0..63 (= 4*wid + (lane>>4))
        const int g  = tid & 15;
        const int v4 = g << 2;
        v2f a01 = {0.f, 0.f}, a23 = {0.f, 0.f};
        for (int k = 0; k < Dn; ++k) {
            const float qq = QmT[k][nl];
            const float4 lv = *reinterpret_cast<const float4*>(&lamS[k][v4]);
            const v2f qv = {qq, qq};
            const v2f l01 = {lv.x, lv.y};
            const v2f l23 = {lv.z, lv.w};
            a01 = a01 + qv * l01;
            a23 = a23 + qv * l23;
        }
        const float a0 = a01.x, a1 = a01.y, a2 = a23.x, a3 = a23.y;

        unsigned su0 = f2u(a0), su1 = f2u(a1), su2 = f2u(a2), su3 = f2u(a3);
        unsigned avail = 0xFu;
        float val0 = 0.f, myval = 0.f;
        int   myidx = 0;

        #pragma unroll
        for (int t = 0; t < TK; ++t) {
            unsigned bu = 0u; int bm = 64;
            if ((avail & 1u) && su0 > bu) { bu = su0; bm = (g << 2) + 0; }
            if ((avail & 2u) && su1 > bu) { bu = su1; bm = (g << 2) + 1; }
            if ((avail & 4u) && su2 > bu) { bu = su2; bm = (g << 2) + 2; }
            if ((avail & 8u) && su3 > bu) { bu = su3; bm = (g << 2) + 3; }
            #pragma unroll
            for (int off = 1; off <= 8; off <<= 1) {
                const unsigned ou = __shfl_xor(bu, off);
                const int      om = __shfl_xor(bm, off);
                if (ou > bu || (ou == bu && om < bm)) { bu = ou; bm = om; }
            }
            const float bv = u2f(bu);
            if (t == 0) val0 = bv;
            if (g == t) { myval = bv; myidx = bm; }
            if ((bm >> 2) == g) avail &= ~(1u << (bm & 3));
        }

        const float ev_own = (g < TK) ? exp_np(myval - val0) : 0.f;
        float s = 0.f;
        #pragma unroll
        for (int t = 0; t < TK; ++t) {
            const float e = __shfl(ev_own, (lane & 48) + t);
            s = s + e;
        }
        const float wfin = ev_own / s;   // valid on g<10; g>=10 never selected below

        // ---- output: wave wid writes out rows (4*wid)*10 .. +39 = 320 contiguous f4 ----
        float* ob = out + (size_t)b * (Nn * TK * Dn);
        const int base4 = wid * 320;
        #pragma unroll
        for (int p = 0; p < 5; ++p) {
            const int i = (p << 6) + lane;       // 0..319
            const int nl4 = i / 80;              // 0..3 local row
            const int r = i - nl4 * 80;
            const int t = r >> 3;
            const int j = r & 7;
            const int src = (nl4 << 4) + t;      // lane holding (row nl4, rank t)
            const float w = __shfl(wfin, src);
            const int   m = __shfl(myidx, src);
            const int  ng = (wid << 2) + nl4;    // global row
            const float4 fr = *reinterpret_cast<const float4*>(&f_sw[ng][(j ^ (ng & 7)) << 2]);
            const float4 cr = *reinterpret_cast<const float4*>(&c_sw[m][(j ^ (m & 7)) << 2]);
            float4 o;
            { const float vx = fr.x * cr.x; o.x = w * vx; }
            { const float vy = fr.y * cr.y; o.y = w * vy; }
            { const float vz = fr.z * cr.z; o.z = w * vz; }
            { const float vw = fr.w * cr.w; o.w = w * vw; }
            reinterpret_cast<float4*>(ob)[base4 + i] = o;
        }
    }
}

extern "C" void kernel_launch(void* const* d_in, const int* in_sizes, int n_in,
                              void* d_out, int out_size, void* d_ws, size_t ws_size,
                              hipStream_t stream) {
    const float* fv = (const float*)d_in[0];   // featureVec [256,64,32]
    const float* cv = (const float*)d_in[1];   // contextVec [256,64,32]
    const float* Wq = (const float*)d_in[2];   // [32,32]
    const float* Wk = (const float*)d_in[3];   // [32,32]
    const float* Wv = (const float*)d_in[4];   // [32,64]
    float* out = (float*)d_out;                // [256, 640, 32]

    sparse_lambda_attn_kernel<<<Bn, NT, 0, stream>>>(fv, cv, Wq, Wk, Wv, out);
}